// Round 5
// baseline (3452.057 us; speedup 1.0000x reference)
//
#include <hip/hip_runtime.h>

// ---------------------------------------------------------------------------
// Two-layer tanh RNN — round 7: MFMA restructure (16-batch clusters).
// B=64, T=512, H=512, I=128, W_OUT=32. fp32 in/out, f16 internal, fp32 acc.
//
// Why: rounds 1/4/5 proved the per-step cost is the h-broadcast DELIVERY
// instruction count (LDS b128 or readlane — invariant ~4-6k cy/CU/step).
// MFMA's B operand is lane-distributed, eliminating the redundancy.
//
// Structure: 8 clusters = {layer 0,1} x {4 bgroups of 16 batches}; cluster
// cl = gid&7 -> XCD cl (rr dispatch); sibling s = gid>>3 (0..31). 256 WGs x
// 1024 thr, 1 WG/CU. Each WG owns 16 rows (s*16..s*16+15) x 16 batches.
// Per step: wave w does 1-2 mfma_f32_16x16x32_f16 (A=weights in regs, B=h
// frags in regs; N=16 batches fills the tile), writes partial C (float2 pair
// per lane) to psumV[t&1]; ONE __syncthreads; threads 768..895 reduce the 16
// K-partials, tanh+noise+bias, pack f16 pairs, post tagged atoms; all waves
// then gather next-step B-frags (4 atoms/tile/lane; h0 pre-issued since L0
// leads). psumV is double-buffered; the tag-dependence chain protects WAR
// across 2 steps, so one barrier/step suffices.
// Exchange: 64-bit {tag32|f16pair} atoms, RELAXED agent scope (proven in
// rounds 1-6). hb0: 64-step ring + consumer-progress throttle (prog = t-2
// posted by L1 s==0; L0 stalls at lead>56; horizon 64). hb1: 4-step ring.
// Stale tags from a previous launch are harmless: equality-match + every
// slot is rewritten by this run before its first colliding read.
// init_pack pre-packs W into A-fragment layout, x into B-fragment layout
// (f32->f16 pairs), zeroes prog.
// FC epilogue: L1 s==0 WGs (one per bgroup).
// ---------------------------------------------------------------------------

#define T_STEPS 512
#define DRING   64
#define THR_LEAD 56

typedef _Float16 half2v __attribute__((ext_vector_type(2)));
typedef _Float16 f16x8  __attribute__((ext_vector_type(8)));
typedef float    f32x4  __attribute__((ext_vector_type(4)));

__device__ __forceinline__ unsigned pack2(float a, float b) {
    _Float16 fa = (_Float16)a, fb = (_Float16)b;
    unsigned short ua = __builtin_bit_cast(unsigned short, fa);
    unsigned short ub = __builtin_bit_cast(unsigned short, fb);
    return (unsigned)ua | ((unsigned)ub << 16);
}

__device__ __forceinline__ float fast_tanh(float xv) {
    float e2 = __builtin_amdgcn_exp2f(xv * 2.885390082f);
    return 1.f - 2.f * __builtin_amdgcn_rcpf(e2 + 1.f);
}

__device__ __forceinline__ f32x4 mfma16(uint4 a, uint4 b, f32x4 c) {
    return __builtin_amdgcn_mfma_f32_16x16x32_f16(
        __builtin_bit_cast(f16x8, a), __builtin_bit_cast(f16x8, b), c, 0, 0, 0);
}

// Poll N tagged atoms concurrently (overlapped RTTs), relaxed agent scope.
template <int N>
__device__ __forceinline__ void pollN(unsigned long long* const (&p)[N],
                                      const unsigned (&tag)[N],
                                      unsigned (&res)[N], long& budget) {
    bool done[N];
#pragma unroll
    for (int i = 0; i < N; ++i) done[i] = false;
    int remaining = N;
    while (remaining > 0 && budget > 0) {
        unsigned long long v[N];
#pragma unroll
        for (int i = 0; i < N; ++i)
            if (!done[i])
                v[i] = __hip_atomic_load(p[i], __ATOMIC_RELAXED, __HIP_MEMORY_SCOPE_AGENT);
#pragma unroll
        for (int i = 0; i < N; ++i)
            if (!done[i] && (unsigned)(v[i] >> 32) == tag[i]) {
                res[i] = (unsigned)v[i]; done[i] = true; --remaining;
            }
        --budget;
    }
}

// Gather one B-fragment tile: 4 consecutive tagged pair-atoms per lane.
__device__ __forceinline__ uint4 gather4(unsigned long long* base, int prb,
                                         unsigned tag, long& budget) {
    unsigned long long* p[4]; unsigned tg[4], res[4];
#pragma unroll
    for (int d = 0; d < 4; ++d) { p[d] = base + prb + d; tg[d] = tag; }
    pollN<4>(p, tg, res, budget);
    return make_uint4(res[0], res[1], res[2], res[3]);
}

// ---- packed sizes (uint4 elements) ----
#define NWA0 (32 * 20 * 64)      // [s][tile<20][lane]  (L0: 4 x-tiles + 16 h-tiles)
#define NWA1 (32 * 32 * 64)      // [s][tile<32][lane]  (L1: 16 h0 + 16 h1)
#define NXP  (512 * 4 * 4 * 64)  // [t][g][kt<4][lane]

// A-frag layout (16x16x32 f16): row = lane&15, k = (lane>>4)*8 + 2d {+0,1}.
// B-frag layout:                col = lane&15, k = (lane>>4)*8 + 2d {+0,1}.
// Same (lane,d)->k formula on both sides => any k-permutation cancels.
__global__ void init_pack(const float* __restrict__ x,
                          const float* __restrict__ Wih0, const float* __restrict__ Whh0,
                          const float* __restrict__ Wih1, const float* __restrict__ Whh1,
                          uint4* __restrict__ wA0, uint4* __restrict__ wA1,
                          uint4* __restrict__ xp, int* __restrict__ prog) {
    int gid = blockIdx.x * 256 + threadIdx.x;
    if (gid < 4) prog[gid] = 0;
    if (gid < NWA0) {
        int s = gid / 1280, rem = gid % 1280, tile = rem >> 6, lane = rem & 63;
        int r = s * 16 + (lane & 15), kb = tile * 32 + (lane >> 4) * 8;
        unsigned dv[4];
#pragma unroll
        for (int d = 0; d < 4; ++d) {
            int k = kb + 2 * d; float w0, w1;
            if (k < 128) { w0 = Wih0[r * 128 + k]; w1 = Wih0[r * 128 + k + 1]; }
            else         { w0 = Whh0[r * 512 + k - 128]; w1 = Whh0[r * 512 + k - 127]; }
            dv[d] = pack2(w0, w1);
        }
        wA0[gid] = make_uint4(dv[0], dv[1], dv[2], dv[3]);
    } else if (gid < NWA0 + NWA1) {
        int idx = gid - NWA0;
        int s = idx / 2048, rem = idx % 2048, tile = rem >> 6, lane = rem & 63;
        int r = s * 16 + (lane & 15), kb = tile * 32 + (lane >> 4) * 8;
        unsigned dv[4];
#pragma unroll
        for (int d = 0; d < 4; ++d) {
            int k = kb + 2 * d; float w0, w1;
            if (k < 512) { w0 = Wih1[r * 512 + k]; w1 = Wih1[r * 512 + k + 1]; }
            else         { w0 = Whh1[r * 512 + k - 512]; w1 = Whh1[r * 512 + k - 511]; }
            dv[d] = pack2(w0, w1);
        }
        wA1[idx] = make_uint4(dv[0], dv[1], dv[2], dv[3]);
    } else if (gid < NWA0 + NWA1 + NXP) {
        int idx = gid - NWA0 - NWA1;
        int t = idx >> 10, rem = idx & 1023;
        int g = rem >> 8, kt = (rem >> 6) & 3, lane = rem & 63;
        int b = g * 16 + (lane & 15), kb = kt * 32 + (lane >> 4) * 8;
        unsigned dv[4];
#pragma unroll
        for (int d = 0; d < 4; ++d) {
            int k = kb + 2 * d;
            dv[d] = pack2(x[((size_t)b * T_STEPS + t) * 128 + k],
                          x[((size_t)b * T_STEPS + t) * 128 + k + 1]);
        }
        xp[idx] = make_uint4(dv[0], dv[1], dv[2], dv[3]);
    }
}

template <int LAYER>
__device__ __forceinline__ void run_layer(
    int s, int g, int L,
    const float* __restrict__ noise,
    const uint4* __restrict__ wA, const uint4* __restrict__ xp,
    const float* __restrict__ bih, const float* __restrict__ bhh,
    unsigned long long* __restrict__ hb0, unsigned long long* __restrict__ hb1,
    int* __restrict__ prog,
    const float* __restrict__ fcw, const float* __restrict__ fcb,
    float* __restrict__ out) {
    const int w = L >> 6, lane = L & 63, col = lane & 15, kg = lane >> 4;
    const int b0 = g * 16, b = b0 + col;
    const bool two = (LAYER == 1) || (w < 4);   // wave-uniform

    long budget = 400000000L;                    // hang bailout only

    // Persistent A-fragments (weights).
    uint4 aA = make_uint4(0, 0, 0, 0), aB;
    if constexpr (LAYER == 1) {
        aA = wA[(s * 32 + w) * 64 + lane];       // h0 tile w
        aB = wA[(s * 32 + 16 + w) * 64 + lane];  // h1 tile 16+w
    } else {
        if (w < 4) { aA = wA[(s * 20 + w) * 64 + lane];          // x tile w
                     aB = wA[(s * 20 + 16 + w) * 64 + lane]; }   // h tile 12+w
        else       { aB = wA[(s * 20 + w) * 64 + lane]; }        // h tile w-4
    }

    // Initial B-fragments (t=0): h(-1)=0.
    uint4 bA = make_uint4(0, 0, 0, 0), bB = make_uint4(0, 0, 0, 0);
    if constexpr (LAYER == 0) {
        if (w < 4) bA = xp[((size_t)0 * 4 + g) * 4 * 64 + w * 64 + lane];
    } else {
        bA = gather4(&hb0[((size_t)0 * 64 + b) * 256], w * 16 + 4 * kg, 1u, budget);
    }

    // Reduce-role precompute (threads 768..895 = waves 12,13).
    const int u = L - 768;
    const int jj = (u >> 6) & 1, lt = u & 63, colr = lt & 15, qq = lt >> 4;
    const int rl0 = 4 * qq + 2 * jj;
    const int r0 = s * 16 + rl0, r1 = r0 + 1;
    const int br = b0 + colr;
    const int pr_post = s * 8 + 2 * qq + jj;
    const bool isRed = (L >= 768 && L < 896);
    float cb0 = 0.f, cb1 = 0.f, nz0 = 0.f, nz1 = 0.f;
    if (isRed) {
        cb0 = bih[r0] + bhh[r0]; cb1 = bih[r1] + bhh[r1];
        nz0 = noise[(((size_t)br * T_STEPS + 0) * 2 + LAYER) * 512 + r0];
        nz1 = noise[(((size_t)br * T_STEPS + 0) * 2 + LAYER) * 512 + r1];
    }
    int known = 0;

    __shared__ float2 psumV[2][2][16][64];       // [parity][regpair][wave][lane]

    for (int t = 0; t < T_STEPS; ++t) {
        const int p = t & 1;
        __builtin_amdgcn_s_setprio(1);

        // ---- (a) MFMA: partial C over this wave's K-tiles ----
        f32x4 C = {0.f, 0.f, 0.f, 0.f};
        if (two) C = mfma16(aA, bA, C);
        C = mfma16(aB, bB, C);
        psumV[p][0][w][lane] = make_float2(C[0], C[1]);   // rows 4q+0,4q+1
        psumV[p][1][w][lane] = make_float2(C[2], C[3]);   // rows 4q+2,4q+3

        __syncthreads();                          // the ONE barrier per step
        const bool last = (t == T_STEPS - 1);

        // ---- (c) reduce 16 partials + tanh + post ----
        if (isRed) {
            float sx = 0.f, sy = 0.f;
#pragma unroll
            for (int ww = 0; ww < 16; ++ww) {
                float2 v = psumV[p][jj][ww][lt]; sx += v.x; sy += v.y;
            }
            float hA = fast_tanh(sx + cb0 + nz0);
            float hB = fast_tanh(sy + cb1 + nz1);
            unsigned pv = pack2(hA, hB);
            unsigned long long atom =
                ((unsigned long long)(unsigned)(t + 1) << 32) | (unsigned long long)pv;
            if constexpr (LAYER == 0) {
                if (t - known > THR_LEAD) {       // ring-overwrite throttle
                    __builtin_amdgcn_s_setprio(0);
                    while (t - known > THR_LEAD && budget > 0) {
                        known = __hip_atomic_load(&prog[g], __ATOMIC_RELAXED,
                                                  __HIP_MEMORY_SCOPE_AGENT);
                        --budget;
                    }
                    __builtin_amdgcn_s_setprio(1);
                }
                __hip_atomic_store(&hb0[((size_t)(t & (DRING - 1)) * 64 + br) * 256 + pr_post],
                                   atom, __ATOMIC_RELAXED, __HIP_MEMORY_SCOPE_AGENT);
            } else {
                __hip_atomic_store(&hb1[((size_t)(t & 3) * 64 + br) * 256 + pr_post],
                                   atom, __ATOMIC_RELAXED, __HIP_MEMORY_SCOPE_AGENT);
            }
            if (!last) {                          // prefetch next-step noise
                nz0 = noise[(((size_t)br * T_STEPS + (t + 1)) * 2 + LAYER) * 512 + r0];
                nz1 = noise[(((size_t)br * T_STEPS + (t + 1)) * 2 + LAYER) * 512 + r1];
            }
        }
        // L1 s==0 publishes consumer progress (all sibs consumed slots <= t-2).
        if constexpr (LAYER == 1) {
            if (s == 0 && L == 960 && t >= 2)
                __hip_atomic_store(&prog[g], t - 2, __ATOMIC_RELAXED,
                                   __HIP_MEMORY_SCOPE_AGENT);
        }

        __builtin_amdgcn_s_setprio(0);
        if (last) break;

        // ---- (d) gather B-fragments for t+1 ----
        if constexpr (LAYER == 0) {
            if (w < 4) bA = xp[(((size_t)(t + 1) * 4 + g) * 4 + w) * 64 + lane];
            const int prb = ((w < 4) ? (12 + w) : (w - 4)) * 16 + 4 * kg;
            bB = gather4(&hb0[((size_t)(t & (DRING - 1)) * 64 + b) * 256], prb,
                         (unsigned)(t + 1), budget);
        } else {
            // pre-issue h0(t+1) loads (L0 leads; tags usually already set)
            unsigned long long* ph[4]; unsigned long long pf[4];
            const size_t h0b = ((size_t)((t + 1) & (DRING - 1)) * 64 + b) * 256
                               + (size_t)(w * 16 + 4 * kg);
#pragma unroll
            for (int d = 0; d < 4; ++d) {
                ph[d] = &hb0[h0b + d];
                pf[d] = __hip_atomic_load(ph[d], __ATOMIC_RELAXED, __HIP_MEMORY_SCOPE_AGENT);
            }
            // h1(t) self-recurrence (posted this step) — the critical wait
            bB = gather4(&hb1[((size_t)(t & 3) * 64 + b) * 256], w * 16 + 4 * kg,
                         (unsigned)(t + 1), budget);
            unsigned rr[4];
#pragma unroll
            for (int d = 0; d < 4; ++d) {
                unsigned long long v = pf[d];
                while ((unsigned)(v >> 32) != (unsigned)(t + 2) && budget > 0) {
                    v = __hip_atomic_load(ph[d], __ATOMIC_RELAXED, __HIP_MEMORY_SCOPE_AGENT);
                    --budget;
                }
                rr[d] = (unsigned)v;
            }
            bA = make_uint4(rr[0], rr[1], rr[2], rr[3]);
        }
    }

    // ---- FC epilogue: out = h1(T-1) @ fc_w^T + fc_b (L1, s==0 WGs) ----
    if constexpr (LAYER == 1) {
        if (s == 0) {
            __shared__ float hs[16][513];
#pragma unroll
            for (int q = 0; q < 4; ++q) {
                int idx = L * 4 + q; int bl = idx >> 8; int pr = idx & 255;
                unsigned long long* pp =
                    &hb1[((size_t)((T_STEPS - 1) & 3) * 64 + (b0 + bl)) * 256 + pr];
                unsigned long long v =
                    __hip_atomic_load(pp, __ATOMIC_RELAXED, __HIP_MEMORY_SCOPE_AGENT);
                while ((unsigned)(v >> 32) != (unsigned)T_STEPS && budget > 0) {
                    v = __hip_atomic_load(pp, __ATOMIC_RELAXED, __HIP_MEMORY_SCOPE_AGENT);
                    --budget;
                }
                half2v h2 = __builtin_bit_cast(half2v, (unsigned)v);
                hs[bl][2 * pr] = (float)h2.x; hs[bl][2 * pr + 1] = (float)h2.y;
            }
            __syncthreads();
            if (L < 512) {
                int bl = L >> 5, o = L & 31;
                float a = fcb[o];
                const float4* wr = (const float4*)(fcw + o * 512);
                for (int k4 = 0; k4 < 128; ++k4) {
                    float4 wv = wr[k4]; const float* hp = &hs[bl][4 * k4];
                    a += wv.x * hp[0] + wv.y * hp[1] + wv.z * hp[2] + wv.w * hp[3];
                }
                out[(b0 + bl) * 32 + o] = a;
            }
        }
    }
}

__global__ __launch_bounds__(1024, 4)
void rnn_mfma(const float* __restrict__ noise,
              const uint4* __restrict__ wA0, const uint4* __restrict__ wA1,
              const uint4* __restrict__ xp,
              const float* __restrict__ bih0, const float* __restrict__ bhh0,
              const float* __restrict__ bih1, const float* __restrict__ bhh1,
              const float* __restrict__ fcw, const float* __restrict__ fcb,
              unsigned long long* __restrict__ hb0, unsigned long long* __restrict__ hb1,
              int* __restrict__ prog, float* __restrict__ out) {
    const int L = threadIdx.x, gid = blockIdx.x;
    const int cl = gid & 7;              // cluster == XCD (rr dispatch)
    const int s = gid >> 3;              // sibling 0..31 (row-tile)
    const int layer = cl >> 2, g = cl & 3;
    if (layer == 0)
        run_layer<0>(s, g, L, noise, wA0, xp, bih0, bhh0, hb0, hb1, prog,
                     nullptr, nullptr, nullptr);
    else
        run_layer<1>(s, g, L, noise, wA1, xp, bih1, bhh1, hb0, hb1, prog,
                     fcw, fcb, out);
}

extern "C" void kernel_launch(void* const* d_in, const int* in_sizes, int n_in,
                              void* d_out, int out_size, void* d_ws, size_t ws_size,
                              hipStream_t stream) {
    const float* x     = (const float*)d_in[0];
    const float* noise = (const float*)d_in[1];
    const float* Wih0  = (const float*)d_in[2];
    const float* Wih1  = (const float*)d_in[3];
    const float* Whh0  = (const float*)d_in[4];
    const float* Whh1  = (const float*)d_in[5];
    const float* bih0  = (const float*)d_in[6];
    const float* bih1  = (const float*)d_in[7];
    const float* bhh0  = (const float*)d_in[8];
    const float* bhh1  = (const float*)d_in[9];
    const float* fcw   = (const float*)d_in[10];
    const float* fcb   = (const float*)d_in[11];
    float* out = (float*)d_out;

    char* ws = (char*)d_ws;
    size_t o = 0;
    uint4* wA0 = (uint4*)(ws + o); o += (size_t)NWA0 * 16;              // 640 KB
    uint4* wA1 = (uint4*)(ws + o); o += (size_t)NWA1 * 16;              // 1 MB
    uint4* xp  = (uint4*)(ws + o); o += (size_t)NXP * 16;               // 8 MB
    unsigned long long* hb0 = (unsigned long long*)(ws + o);
    o += (size_t)DRING * 64 * 256 * 8;                                  // 8 MB ring
    unsigned long long* hb1 = (unsigned long long*)(ws + o);
    o += (size_t)4 * 64 * 256 * 8;                                      // 512 KB ring
    int* prog = (int*)(ws + o); o += 16 * sizeof(int);

    const int total = NWA0 + NWA1 + NXP;
    init_pack<<<(total + 255) / 256, 256, 0, stream>>>(x, Wih0, Whh0, Wih1, Whh1,
                                                       wA0, wA1, xp, prog);
    rnn_mfma<<<256, 1024, 0, stream>>>(noise, wA0, wA1, xp, bih0, bhh0, bih1, bhh1,
                                       fcw, fcb, hb0, hb1, prog, out);
}

// Round 6
// 1111.285 us; speedup vs baseline: 3.1064x; 3.1064x over previous
//
#include <hip/hip_runtime.h>

// ---------------------------------------------------------------------------
// Two-layer tanh RNN — round 8: per-wave private chunks, readiness-split dots.
// B=64, T=512, H=512, I=128, W_OUT=32. fp32 in/out, f16-pair internal, fp32 acc.
//
// Keeps R3 champion's cluster/exchange protocol (64 clusters = layer x pair,
// 4 sibling WGs x 1024 thr, 1 WG/CU, tagged {tag|f16pair} atoms, DRING=256 +
// throttle, h0 prefetch, FC in L1 s==0). Changes:
//  - 16 chunks/WG, ONE wave per chunk, each lane owns 2 rows (halves LDS
//    broadcast delivery). Chunk data lives in a PRIVATE per-wave LDS strip.
//  - Chunks split by readiness: A-chunks (x, own h via hown, prefetched h0)
//    dot immediately at step start; B-chunks (remote h) self-gather their
//    atoms (1/lane) then dot — no barrier between gather and its dots, so
//    the MALL RTT hides under A-dots instead of serializing the step.
//  - 2 barriers/step: psum->reduce, reduce->next-step (protects hown+psum).
//  - Epoch tag: tags = (epoch<<10)+t+1; init_pack bumps epoch — replay-safe.
// Roles: L0: w0-11 remote-h0 (6 chunks x 2 batch-waves), w12-13 own-h0,
//        w14-15 x. L1: w0-7 h0 (prefetch), w8-9 own-h1, w10-15 remote-h1.
// ---------------------------------------------------------------------------

#define T_STEPS 512
#define NBATCH  64
#define DRING   256
#define THR_LEAD 192

typedef _Float16 half2v __attribute__((ext_vector_type(2)));

__device__ __forceinline__ unsigned pack2(float a, float b) {
    _Float16 fa = (_Float16)a, fb = (_Float16)b;
    unsigned short ua = __builtin_bit_cast(unsigned short, fa);
    unsigned short ub = __builtin_bit_cast(unsigned short, fb);
    return (unsigned)ua | ((unsigned)ub << 16);
}

__device__ __forceinline__ float dot2acc(unsigned w, unsigned h, float acc) {
#if __has_builtin(__builtin_amdgcn_fdot2)
    return __builtin_amdgcn_fdot2(__builtin_bit_cast(half2v, w),
                                  __builtin_bit_cast(half2v, h), acc, false);
#else
    half2v wv = __builtin_bit_cast(half2v, w);
    half2v hv = __builtin_bit_cast(half2v, h);
    acc = fmaf((float)wv.x, (float)hv.x, acc);
    return fmaf((float)wv.y, (float)hv.y, acc);
#endif
}

__device__ __forceinline__ float fast_tanh(float xv) {
    float e2 = __builtin_amdgcn_exp2f(xv * 2.885390082f);
    return 1.f - 2.f * __builtin_amdgcn_rcpf(e2 + 1.f);
}

__device__ __forceinline__ unsigned poll1(unsigned long long* p, unsigned tag,
                                          long& budget) {
    unsigned long long v = __hip_atomic_load(p, __ATOMIC_RELAXED, __HIP_MEMORY_SCOPE_AGENT);
    while ((unsigned)(v >> 32) != tag && budget > 0) {
        v = __hip_atomic_load(p, __ATOMIC_RELAXED, __HIP_MEMORY_SCOPE_AGENT);
        --budget;
    }
    return (unsigned)v;
}

// Packed weights: wp[(base + rr*32 + j)*64 + lane], row r = s*128 + 2*lane + rr.
// L0 base = (s*10 + cs)*64: cs 0-5 remote-h0 (m=cs*32+j, p0 = m<s*64?m:m+64),
//   cs 6-7 own-h0 (p0 = s*64+(cs-6)*32+j), cs 8-9 x (px=(cs-8)*32+j).
// L1 base = (s*16 + w)*64: w0-7 h0 (p=w*32+j), w8-9 own-h1, w10-15 remote-h1.
#define NW0 (4 * 10 * 64 * 64)
#define NW1 (4 * 16 * 64 * 64)

__global__ void init_pack(const float* __restrict__ Wih0, const float* __restrict__ Whh0,
                          const float* __restrict__ Wih1, const float* __restrict__ Whh1,
                          unsigned* __restrict__ wp0, unsigned* __restrict__ wp1,
                          int* __restrict__ prog) {
    int gid = blockIdx.x * 256 + threadIdx.x;
    if (gid == 32) prog[32] = prog[32] + 1;   // epoch bump (replay-unique tags)
    if (gid < 32) prog[gid] = 0;
    if (gid < NW0) {
        int lane = gid & 63, slot = (gid >> 6) & 63, t12 = gid >> 12;
        int cs = t12 % 10, s = t12 / 10;
        int rr = slot >> 5, j = slot & 31;
        int r = s * 128 + 2 * lane + rr;
        float w0, w1;
        if (cs < 6)      { int m = cs * 32 + j; int p0 = (m < s * 64) ? m : m + 64;
                           w0 = Whh0[r * 512 + 2 * p0]; w1 = Whh0[r * 512 + 2 * p0 + 1]; }
        else if (cs < 8) { int p0 = s * 64 + (cs - 6) * 32 + j;
                           w0 = Whh0[r * 512 + 2 * p0]; w1 = Whh0[r * 512 + 2 * p0 + 1]; }
        else             { int px = (cs - 8) * 32 + j;
                           w0 = Wih0[r * 128 + 2 * px]; w1 = Wih0[r * 128 + 2 * px + 1]; }
        wp0[gid] = pack2(w0, w1);
    } else if (gid < NW0 + NW1) {
        int g2 = gid - NW0;
        int lane = g2 & 63, slot = (g2 >> 6) & 63, w = (g2 >> 12) & 15, s = g2 >> 16;
        int rr = slot >> 5, j = slot & 31;
        int r = s * 128 + 2 * lane + rr;
        float w0, w1;
        if (w < 8)       { int p = w * 32 + j;
                           w0 = Wih1[r * 512 + 2 * p]; w1 = Wih1[r * 512 + 2 * p + 1]; }
        else if (w < 10) { int p1 = s * 64 + (w - 8) * 32 + j;
                           w0 = Whh1[r * 512 + 2 * p1]; w1 = Whh1[r * 512 + 2 * p1 + 1]; }
        else             { int m = (w - 10) * 32 + j; int p1 = (m < s * 64) ? m : m + 64;
                           w0 = Whh1[r * 512 + 2 * p1]; w1 = Whh1[r * 512 + 2 * p1 + 1]; }
        wp1[g2] = pack2(w0, w1);
    }
}

template <int LAYER>
__device__ __forceinline__ void run_layer(
    int b0, int s, int L, int pair,
    const float* __restrict__ x, const float* __restrict__ noise,
    const unsigned* __restrict__ wp,
    const float* __restrict__ bih, const float* __restrict__ bhh,
    unsigned long long* __restrict__ hb0, unsigned long long* __restrict__ hb1,
    int* __restrict__ prog,
    const float* __restrict__ fcw, const float* __restrict__ fcb,
    float* __restrict__ out) {
    const int w = L >> 6, lane = L & 63;
    const unsigned tagbase = ((unsigned)prog[32]) << 10;
    long budget = 2000000000L;

    // ---- persistent weights: 64 dwords/lane (2 rows x 32 pairs) ----
    int wbase;
    if constexpr (LAYER == 0) { int cs = (w < 12) ? (w >> 1) : (w - 6); wbase = (s * 10 + cs) * 64; }
    else                      { wbase = (s * 16 + w) * 64; }
    unsigned wreg[64];
#pragma unroll
    for (int i = 0; i < 64; ++i) {
        wreg[i] = wp[(size_t)(wbase + i) * 64 + lane];
        asm volatile("" : "+v"(wreg[i]));
    }

    __shared__ float psum[16][2][128];                 // [chunk][batch][row]
    __shared__ __align__(16) unsigned priv[16][64];    // per-wave strips
    __shared__ __align__(16) unsigned hown[128];       // own pairs [p_local*2+bb]
    for (int i = L; i < 16 * 64; i += 1024) ((unsigned*)priv)[i] = 0u;
    if (L < 128) hown[L] = 0u;                         // h(-1) = 0

    // reduce-role constants (lanes 0..255: bb = L>>7, row rw = L&127)
    const bool isRed = (L < 256);
    const int bbr = L >> 7, rw = L & 127;
    const int rgl = s * 128 + rw;
    float cb = 0.f, nz = 0.f;
    if (isRed) {
        cb = bih[rgl] + bhh[rgl];
        nz = noise[(((size_t)(b0 + bbr) * T_STEPS + 0) * 2 + LAYER) * 512 + rgl];
    }
    __syncthreads();

    // ---- pre-loop staging ----
    unsigned long long pf = 0;
    float2 xf = make_float2(0.f, 0.f);
    if constexpr (LAYER == 1) {
        if (w < 8) {   // h0(0): blocking poll (L0 computes it in its step 0)
            unsigned v = poll1(&hb0[((size_t)0 * NBATCH + (b0 + (lane >> 5))) * 256 +
                                    (w * 32 + (lane & 31))], tagbase + 1, budget);
            pf = ((unsigned long long)(tagbase + 1) << 32) | v;
        }
    } else {
        if (w >= 14) {
            int j = lane & 31, bbl = lane >> 5;
            int px = (w - 14) * 32 + j;
            xf = *(const float2*)(x + ((size_t)(b0 + bbl) * T_STEPS + 0) * 128 + 2 * px);
        }
    }

    int known = 0;

    for (int t = 0; t < T_STEPS; ++t) {
        const bool last = (t == T_STEPS - 1);
        __builtin_amdgcn_s_setprio(1);

        // ---- per-wave staging (A: instant; B: self-gather, RTT hides under A-dots) ----
        if constexpr (LAYER == 1) {
            if (w < 8) {                                  // h0(t): confirm prefetch
                const int j = lane & 31, bbl = lane >> 5;
                unsigned want = tagbase + (unsigned)t + 1;
                if ((unsigned)(pf >> 32) != want) {
                    __builtin_amdgcn_s_setprio(0);
                    unsigned v = poll1(&hb0[((size_t)(t & (DRING - 1)) * NBATCH + (b0 + bbl)) * 256 +
                                            (w * 32 + j)], want, budget);
                    pf = ((unsigned long long)want << 32) | v;
                    __builtin_amdgcn_s_setprio(1);
                }
                priv[w][j * 2 + bbl] = (unsigned)pf;
                if (!last)                                 // issue next prefetch
                    pf = __hip_atomic_load(&hb0[((size_t)((t + 1) & (DRING - 1)) * NBATCH +
                                                 (b0 + bbl)) * 256 + (w * 32 + j)],
                                           __ATOMIC_RELAXED, __HIP_MEMORY_SCOPE_AGENT);
            } else if (w >= 10) {                         // remote h1(t-1)
                if (t > 0) {
                    const int j = lane & 31, bbl = lane >> 5;
                    int m = (w - 10) * 32 + j;
                    int p2 = (m < s * 64) ? m : m + 64;
                    __builtin_amdgcn_s_setprio(0);
                    unsigned v = poll1(&hb1[((size_t)((t - 1) & 3) * NBATCH + (b0 + bbl)) * 256 + p2],
                                       tagbase + (unsigned)t, budget);
                    __builtin_amdgcn_s_setprio(1);
                    priv[w][j * 2 + bbl] = v;
                }
            }
        } else {
            if (w < 12) {                                 // remote h0(t-1), 1 batch/wave
                if (t > 0 && lane < 32) {
                    int q = w >> 1, bbw = w & 1;
                    int m = q * 32 + lane;
                    int p2 = (m < s * 64) ? m : m + 64;
                    __builtin_amdgcn_s_setprio(0);
                    unsigned v = poll1(&hb0[((size_t)((t - 1) & (DRING - 1)) * NBATCH +
                                             (b0 + bbw)) * 256 + p2],
                                       tagbase + (unsigned)t, budget);
                    __builtin_amdgcn_s_setprio(1);
                    priv[w][lane] = v;
                }
            } else if (w >= 14) {                         // x(t) pack + x(t+1) prefetch
                const int j = lane & 31, bbl = lane >> 5;
                priv[w][j * 2 + bbl] = pack2(xf.x, xf.y);
                if (!last) {
                    int px = (w - 14) * 32 + j;
                    xf = *(const float2*)(x + ((size_t)(b0 + bbl) * T_STEPS + (t + 1)) * 128 + 2 * px);
                }
            }
        }

        float nznext = 0.f;
        if (!last && isRed)
            nznext = noise[(((size_t)(b0 + bbr) * T_STEPS + (t + 1)) * 2 + LAYER) * 512 + rgl];

        // ---- dots: each wave, its chunk, 2 rows/lane ----
        if constexpr (LAYER == 0) {
            if (w < 12) {                                 // single batch
                const int q = w >> 1, bbw = w & 1;
                const uint4* hq = (const uint4*)&priv[w][0];   // 8 uint4, [pair]
                float ax[2] = {0.f, 0.f}, ay[2] = {0.f, 0.f};
#pragma unroll
                for (int k = 0; k < 8; ++k) {
                    uint4 v = hq[k];
#pragma unroll
                    for (int r2 = 0; r2 < 2; ++r2) {
                        ax[r2] = dot2acc(wreg[r2 * 32 + 4 * k + 0], v.x, ax[r2]);
                        ay[r2] = dot2acc(wreg[r2 * 32 + 4 * k + 1], v.y, ay[r2]);
                        ax[r2] = dot2acc(wreg[r2 * 32 + 4 * k + 2], v.z, ax[r2]);
                        ay[r2] = dot2acc(wreg[r2 * 32 + 4 * k + 3], v.w, ay[r2]);
                    }
                }
                *(float2*)&psum[q][bbw][2 * lane] =
                    make_float2(ax[0] + ay[0], ax[1] + ay[1]);
            } else {                                      // own-h0 / x: both batches
                const uint4* hq = (w < 14) ? (const uint4*)&hown[(w - 12) * 64]
                                           : (const uint4*)&priv[w][0];
                const int pidx = (w < 14) ? (6 + (w - 12)) : (8 + (w - 14));
                float a[2][2] = {{0.f, 0.f}, {0.f, 0.f}};
                float b2[2][2] = {{0.f, 0.f}, {0.f, 0.f}};
#pragma unroll
                for (int k = 0; k < 16; ++k) {
                    uint4 v = hq[k];
                    const int j0 = 2 * k, j1 = 2 * k + 1;
#pragma unroll
                    for (int r2 = 0; r2 < 2; ++r2) {
                        a[r2][0]  = dot2acc(wreg[r2 * 32 + j0], v.x, a[r2][0]);
                        a[r2][1]  = dot2acc(wreg[r2 * 32 + j0], v.y, a[r2][1]);
                        b2[r2][0] = dot2acc(wreg[r2 * 32 + j1], v.z, b2[r2][0]);
                        b2[r2][1] = dot2acc(wreg[r2 * 32 + j1], v.w, b2[r2][1]);
                    }
                }
#pragma unroll
                for (int bb2 = 0; bb2 < 2; ++bb2)
                    *(float2*)&psum[pidx][bb2][2 * lane] =
                        make_float2(a[0][bb2] + b2[0][bb2], a[1][bb2] + b2[1][bb2]);
            }
        } else {
            const uint4* hq = (w == 8 || w == 9) ? (const uint4*)&hown[(w - 8) * 64]
                                                 : (const uint4*)&priv[w][0];
            float a[2][2] = {{0.f, 0.f}, {0.f, 0.f}};
            float b2[2][2] = {{0.f, 0.f}, {0.f, 0.f}};
#pragma unroll
            for (int k = 0; k < 16; ++k) {
                uint4 v = hq[k];
                const int j0 = 2 * k, j1 = 2 * k + 1;
#pragma unroll
                for (int r2 = 0; r2 < 2; ++r2) {
                    a[r2][0]  = dot2acc(wreg[r2 * 32 + j0], v.x, a[r2][0]);
                    a[r2][1]  = dot2acc(wreg[r2 * 32 + j0], v.y, a[r2][1]);
                    b2[r2][0] = dot2acc(wreg[r2 * 32 + j1], v.z, b2[r2][0]);
                    b2[r2][1] = dot2acc(wreg[r2 * 32 + j1], v.w, b2[r2][1]);
                }
            }
#pragma unroll
            for (int bb2 = 0; bb2 < 2; ++bb2)
                *(float2*)&psum[w][bb2][2 * lane] =
                    make_float2(a[0][bb2] + b2[0][bb2], a[1][bb2] + b2[1][bb2]);
        }

        __syncthreads();                                  // barrier b: psum ready

        // ---- reduce + tanh + post + own write ----
        if (isRed) {
            constexpr int NCH = (LAYER == 0) ? 10 : 16;
            float sum = 0.f;
#pragma unroll
            for (int ch = 0; ch < NCH; ++ch) sum += psum[ch][bbr][rw];
            float h = fast_tanh(sum + cb + nz);
            float hnb = __shfl_down(h, 1);
            if ((L & 1) == 0) {
                unsigned pv = pack2(h, hnb);
                int pr = s * 64 + (rw >> 1);
                unsigned long long atom =
                    ((unsigned long long)(tagbase + (unsigned)t + 1) << 32) |
                    (unsigned long long)pv;
                if constexpr (LAYER == 0) {
                    if (t - known > THR_LEAD) {           // ring-overwrite throttle
                        __builtin_amdgcn_s_setprio(0);
                        while (t - known > THR_LEAD && budget > 0) {
                            known = __hip_atomic_load(&prog[pair], __ATOMIC_RELAXED,
                                                      __HIP_MEMORY_SCOPE_AGENT);
                            --budget;
                        }
                        __builtin_amdgcn_s_setprio(1);
                    }
                    __hip_atomic_store(&hb0[((size_t)(t & (DRING - 1)) * NBATCH + (b0 + bbr)) * 256 + pr],
                                       atom, __ATOMIC_RELAXED, __HIP_MEMORY_SCOPE_AGENT);
                } else {
                    __hip_atomic_store(&hb1[((size_t)(t & 3) * NBATCH + (b0 + bbr)) * 256 + pr],
                                       atom, __ATOMIC_RELAXED, __HIP_MEMORY_SCOPE_AGENT);
                }
                hown[(rw >> 1) * 2 + bbr] = pv;
            }
            nz = nznext;
        }
        if constexpr (LAYER == 1) {                       // consumer progress
            if (s == 0 && L == 960 && t > 1)
                __hip_atomic_store(&prog[pair], t - 2, __ATOMIC_RELAXED,
                                   __HIP_MEMORY_SCOPE_AGENT);
        }
        __syncthreads();                                  // barrier c: hown/psum safe
        __builtin_amdgcn_s_setprio(0);
    }

    // ---- FC epilogue: out = h1(T-1) @ fc_w^T + fc_b (L1 s==0 WGs) ----
    if constexpr (LAYER == 1) {
        if (s == 0) {
            __shared__ float hs[2][512];
            __shared__ float part[2][512];
            if (L < 512) {
                int bl = L >> 8, pr = L & 255;
                unsigned v = poll1(&hb1[((size_t)((T_STEPS - 1) & 3) * NBATCH + (b0 + bl)) * 256 + pr],
                                   tagbase + (unsigned)T_STEPS, budget);
                half2v h2 = __builtin_bit_cast(half2v, v);
                hs[bl][2 * pr] = (float)h2.x; hs[bl][2 * pr + 1] = (float)h2.y;
            }
            __syncthreads();
            {
                int bl = L >> 9, rest = L & 511, o = rest & 31, seg = rest >> 5;
                const float* wr = fcw + o * 512 + seg * 32;
                const float* hr = &hs[bl][seg * 32];
                float a = 0.f;
#pragma unroll
                for (int k = 0; k < 32; ++k) a = fmaf(wr[k], hr[k], a);
                part[bl][rest] = a;
            }
            __syncthreads();
            if (L < 64) {
                int bl = L >> 5, o = L & 31;
                float ssum = fcb[o];
#pragma unroll
                for (int sgi = 0; sgi < 16; ++sgi) ssum += part[bl][sgi * 32 + o];
                out[(b0 + bl) * 32 + o] = ssum;
            }
        }
    }
}

__global__ __launch_bounds__(1024, 4)
void rnn_dual(const float* __restrict__ x, const float* __restrict__ noise,
              const unsigned* __restrict__ wp0, const unsigned* __restrict__ wp1,
              const float* __restrict__ bih0, const float* __restrict__ bhh0,
              const float* __restrict__ bih1, const float* __restrict__ bhh1,
              const float* __restrict__ fcw, const float* __restrict__ fcb,
              unsigned long long* __restrict__ hb0,
              unsigned long long* __restrict__ hb1,
              int* __restrict__ prog,
              float* __restrict__ out) {
    const int L = threadIdx.x;
    const int gid = blockIdx.x;
    const int cl = gid & 63;             // cluster: layer*32 + pair
    const int s = gid >> 6;              // sibling quarter 0..3
    const int layer = cl >> 5;
    const int pair = cl & 31;
    const int b0 = pair * 2;             // gid%8 == cl%8: co-XCD (locality only)
    if (layer == 0)
        run_layer<0>(b0, s, L, pair, x, noise, wp0, bih0, bhh0,
                     hb0, hb1, prog, nullptr, nullptr, nullptr);
    else
        run_layer<1>(b0, s, L, pair, x, noise, wp1, bih1, bhh1,
                     hb0, hb1, prog, fcw, fcb, out);
}

extern "C" void kernel_launch(void* const* d_in, const int* in_sizes, int n_in,
                              void* d_out, int out_size, void* d_ws, size_t ws_size,
                              hipStream_t stream) {
    const float* x     = (const float*)d_in[0];
    const float* noise = (const float*)d_in[1];
    const float* Wih0  = (const float*)d_in[2];
    const float* Wih1  = (const float*)d_in[3];
    const float* Whh0  = (const float*)d_in[4];
    const float* Whh1  = (const float*)d_in[5];
    const float* bih0  = (const float*)d_in[6];
    const float* bih1  = (const float*)d_in[7];
    const float* bhh0  = (const float*)d_in[8];
    const float* bhh1  = (const float*)d_in[9];
    const float* fcw   = (const float*)d_in[10];
    const float* fcb   = (const float*)d_in[11];
    float* out = (float*)d_out;

    char* ws = (char*)d_ws;
    size_t o = 0;
    unsigned* wp0 = (unsigned*)(ws + o); o += (size_t)NW0 * 4;  // 640 KB
    unsigned* wp1 = (unsigned*)(ws + o); o += (size_t)NW1 * 4;  // 1 MB
    unsigned long long* hb0 = (unsigned long long*)(ws + o);
    o += (size_t)DRING * NBATCH * 256 * 8;                      // 33.5 MB ring
    unsigned long long* hb1 = (unsigned long long*)(ws + o);
    o += (size_t)4 * NBATCH * 256 * 8;                          // 512 KB ring
    int* prog = (int*)(ws + o); o += 33 * sizeof(int);          // prog + epoch

    const int total = NW0 + NW1;
    init_pack<<<(total + 255) / 256, 256, 0, stream>>>(Wih0, Whh0, Wih1, Whh1,
                                                       wp0, wp1, prog);
    rnn_dual<<<256, 1024, 0, stream>>>(x, noise, wp0, wp1, bih0, bhh0, bih1, bhh1,
                                       fcw, fcb, hb0, hb1, prog, out);
}